// Round 1
// baseline (3087.738 us; speedup 1.0000x reference)
//
#include <hip/hip_runtime.h>
#include <hip/hip_bf16.h>
#include <math.h>

#define B_ 16
#define S_ 1024
#define D_ 256
#define H_ 8
#define L_ 4
#define DH_ 32
#define OBS_ 160
#define ACT_ 96
#define M_ (B_*S_)   // 16384

// ---------------------------------------------------------------- RoPE table
__global__ __launch_bounds__(256) void rope_table_k(float* __restrict__ cosT,
                                                    float* __restrict__ sinT) {
    int idx = blockIdx.x * 256 + threadIdx.x;
    if (idx >= S_ * 16) return;
    int s = idx >> 4, i = idx & 15;
    float e = (float)(2 * i) / (float)DH_;
    float invf = powf(10000.0f, -e);
    float ang = (float)s * invf;
    float sn, cs;
    sincosf(ang, &sn, &cs);
    cosT[idx] = cs;
    sinT[idx] = sn;
}

// ---------------------------------------------------------------- GEMM
// C(M x 256) = A(M x 256) @ W(256 x 256) + bias  [+ residual]
// AMODE: 0 = plain A, 1 = concat(obs,act)
// EPI:   0 = plain store, 1 = plain + residual, 2 = heads scatter, 3 = heads + rope
template<int AMODE, int EPI>
__global__ __launch_bounds__(256) void gemm_k(
    const float* __restrict__ A, const float* __restrict__ obs,
    const float* __restrict__ act, const float* __restrict__ W,
    const float* __restrict__ bias, const float* __restrict__ resid,
    float* __restrict__ out, const float* __restrict__ cosT,
    const float* __restrict__ sinT)
{
    __shared__ float As[16][68];   // [k][m], padded
    __shared__ float Ws[16][64];   // [k][n]
    const int tid = threadIdx.x;
    const int tx = tid & 15, ty = tid >> 4;
    const int bcol = blockIdx.x * 64;
    const int brow = blockIdx.y * 64;

    const int arow = brow + (tid >> 2);
    const int ac0  = (tid & 3) * 4;
    const int wrow = tid >> 4;
    const int wc0  = (tid & 15) * 4;

    float acc[4][4];
    #pragma unroll
    for (int i = 0; i < 4; ++i)
        #pragma unroll
        for (int j = 0; j < 4; ++j) acc[i][j] = 0.f;

    for (int bk = 0; bk < 256; bk += 16) {
        float4 av, wv;
        if (AMODE == 0) {
            av = *(const float4*)&A[arow * 256 + bk + ac0];
        } else {
            int c = bk + ac0;
            if (c < OBS_) av = *(const float4*)&obs[arow * OBS_ + c];
            else          av = *(const float4*)&act[arow * ACT_ + (c - OBS_)];
        }
        wv = *(const float4*)&W[(bk + wrow) * 256 + bcol + wc0];
        __syncthreads();
        As[ac0 + 0][tid >> 2] = av.x;
        As[ac0 + 1][tid >> 2] = av.y;
        As[ac0 + 2][tid >> 2] = av.z;
        As[ac0 + 3][tid >> 2] = av.w;
        *(float4*)&Ws[wrow][wc0] = wv;
        __syncthreads();
        #pragma unroll
        for (int kk = 0; kk < 16; ++kk) {
            const float4 a = *(const float4*)&As[kk][ty * 4];
            const float4 b = *(const float4*)&Ws[kk][tx * 4];
            const float ar[4] = {a.x, a.y, a.z, a.w};
            const float br[4] = {b.x, b.y, b.z, b.w};
            #pragma unroll
            for (int i = 0; i < 4; ++i)
                #pragma unroll
                for (int j = 0; j < 4; ++j)
                    acc[i][j] = fmaf(ar[i], br[j], acc[i][j]);
        }
    }

    const int col = bcol + tx * 4;
    if (EPI <= 1) {
        #pragma unroll
        for (int i = 0; i < 4; ++i) {
            int row = brow + ty * 4 + i;
            float4 o;
            o.x = acc[i][0] + bias[col + 0];
            o.y = acc[i][1] + bias[col + 1];
            o.z = acc[i][2] + bias[col + 2];
            o.w = acc[i][3] + bias[col + 3];
            if (EPI == 1) {
                const float4 r = *(const float4*)&resid[row * 256 + col];
                o.x += r.x; o.y += r.y; o.z += r.z; o.w += r.w;
            }
            *(float4*)&out[row * 256 + col] = o;
        }
    } else {
        const int h  = col >> 5;
        const int dh = col & 31;
        const float b0 = bias[col + 0], b1 = bias[col + 1];
        const float b2 = bias[col + 2], b3 = bias[col + 3];
        #pragma unroll
        for (int i = 0; i < 4; ++i) {
            int row = brow + ty * 4 + i;
            int bb = row >> 10, ss = row & (S_ - 1);
            float v0 = acc[i][0] + b0, v1 = acc[i][1] + b1;
            float v2 = acc[i][2] + b2, v3 = acc[i][3] + b3;
            if (EPI == 3) {
                int ip = dh >> 1;
                float cs0 = cosT[ss * 16 + ip],     sn0 = sinT[ss * 16 + ip];
                float cs1 = cosT[ss * 16 + ip + 1], sn1 = sinT[ss * 16 + ip + 1];
                float o0 = v0 * cs0 - v1 * sn0;
                float o1 = v0 * sn0 + v1 * cs0;
                float o2 = v2 * cs1 - v3 * sn1;
                float o3 = v2 * sn1 + v3 * cs1;
                v0 = o0; v1 = o1; v2 = o2; v3 = o3;
            }
            int base = ((bb * H_ + h) * S_ + ss) * DH_ + dh;
            *(float4*)&out[base] = make_float4(v0, v1, v2, v3);
        }
    }
}

// ---------------------------------------------------------------- Attention
// q,k,v in (B,H,S,DH); out in (B,S,D). Streaming softmax, 2 q-rows/thread.
__global__ __launch_bounds__(256) void attn_k(
    const float* __restrict__ q, const float* __restrict__ k,
    const float* __restrict__ v, float* __restrict__ out)
{
    __shared__ float Ks[64][36];
    __shared__ float Vs[64][36];
    const int tid  = threadIdx.x;
    const int bh   = blockIdx.x >> 1;   // 0..127
    const int half = blockIdx.x & 1;
    const int bb = bh >> 3, hh = bh & 7;
    const int sq0 = half * 512 + tid;
    const int sq1 = sq0 + 256;

    float q0[32], q1[32], a0[32], a1[32];
    const float* qp0 = q + (bh * S_ + sq0) * DH_;
    const float* qp1 = q + (bh * S_ + sq1) * DH_;
    #pragma unroll
    for (int d = 0; d < 32; d += 4) {
        float4 t0 = *(const float4*)&qp0[d];
        q0[d] = t0.x; q0[d+1] = t0.y; q0[d+2] = t0.z; q0[d+3] = t0.w;
        float4 t1 = *(const float4*)&qp1[d];
        q1[d] = t1.x; q1[d+1] = t1.y; q1[d+2] = t1.z; q1[d+3] = t1.w;
        a0[d] = a0[d+1] = a0[d+2] = a0[d+3] = 0.f;
        a1[d] = a1[d+1] = a1[d+2] = a1[d+3] = 0.f;
    }
    float m0 = -3e38f, m1 = -3e38f, l0 = 0.f, l1 = 0.f;
    const float* kp = k + bh * S_ * DH_;
    const float* vp = v + bh * S_ * DH_;
    const int lr = tid >> 2, ld0 = (tid & 3) * 8;

    for (int kt = 0; kt < S_; kt += 64) {
        float4 ka = *(const float4*)&kp[(kt + lr) * DH_ + ld0];
        float4 kb = *(const float4*)&kp[(kt + lr) * DH_ + ld0 + 4];
        float4 va = *(const float4*)&vp[(kt + lr) * DH_ + ld0];
        float4 vb = *(const float4*)&vp[(kt + lr) * DH_ + ld0 + 4];
        __syncthreads();
        *(float4*)&Ks[lr][ld0]     = ka;
        *(float4*)&Ks[lr][ld0 + 4] = kb;
        *(float4*)&Vs[lr][ld0]     = va;
        *(float4*)&Vs[lr][ld0 + 4] = vb;
        __syncthreads();
        for (int j = 0; j < 64; ++j) {
            float s0 = 0.f, s1 = 0.f;
            #pragma unroll
            for (int d = 0; d < 32; ++d) {
                float kv = Ks[j][d];
                s0 = fmaf(q0[d], kv, s0);
                s1 = fmaf(q1[d], kv, s1);
            }
            s0 *= 0.17677669529663687f;
            s1 *= 0.17677669529663687f;
            float mn0 = fmaxf(m0, s0), mn1 = fmaxf(m1, s1);
            float p0 = __expf(s0 - mn0), p1 = __expf(s1 - mn1);
            float c0 = __expf(m0 - mn0), c1 = __expf(m1 - mn1);
            l0 = l0 * c0 + p0; l1 = l1 * c1 + p1;
            m0 = mn0; m1 = mn1;
            #pragma unroll
            for (int d = 0; d < 32; ++d) {
                float vv = Vs[j][d];
                a0[d] = a0[d] * c0 + p0 * vv;
                a1[d] = a1[d] * c1 + p1 * vv;
            }
        }
    }
    float inv0 = 1.f / l0, inv1 = 1.f / l1;
    float* o0 = out + (bb * S_ + sq0) * D_ + hh * DH_;
    float* o1 = out + (bb * S_ + sq1) * D_ + hh * DH_;
    #pragma unroll
    for (int d = 0; d < 32; d += 4) {
        *(float4*)&o0[d] = make_float4(a0[d]*inv0, a0[d+1]*inv0, a0[d+2]*inv0, a0[d+3]*inv0);
        *(float4*)&o1[d] = make_float4(a1[d]*inv1, a1[d+1]*inv1, a1[d+2]*inv1, a1[d+3]*inv1);
    }
}

// ---------------------------------------------------------------- LayerNorm
__global__ __launch_bounds__(256) void ln_k(
    const float* __restrict__ y, const float* __restrict__ g,
    const float* __restrict__ bta, float* __restrict__ outp)
{
    const int tid = threadIdx.x;
    const int wave = tid >> 6, lane = tid & 63;
    const int row = blockIdx.x * 4 + wave;
    const int col = lane * 4;
    float4 t = *(const float4*)&y[row * 256 + col];
    float sum = t.x + t.y + t.z + t.w;
    float ss  = t.x*t.x + t.y*t.y + t.z*t.z + t.w*t.w;
    #pragma unroll
    for (int off = 32; off; off >>= 1) {
        sum += __shfl_xor(sum, off);
        ss  += __shfl_xor(ss, off);
    }
    float mean = sum * (1.f / 256.f);
    float var  = ss * (1.f / 256.f) - mean * mean;
    float rstd = rsqrtf(var + 1e-5f);
    float4 gv = *(const float4*)&g[col];
    float4 bv = *(const float4*)&bta[col];
    float4 o;
    o.x = (t.x - mean) * rstd * gv.x + bv.x;
    o.y = (t.y - mean) * rstd * gv.y + bv.y;
    o.z = (t.z - mean) * rstd * gv.z + bv.z;
    o.w = (t.w - mean) * rstd * gv.w + bv.w;
    float* seq = outp + B_ * D_;
    *(float4*)&seq[row * 256 + col] = o;
    if ((row & (S_ - 1)) == S_ - 1) {
        *(float4*)&outp[(row >> 10) * 256 + col] = o;
    }
}

// ---------------------------------------------------------------- launch
extern "C" void kernel_launch(void* const* d_in, const int* in_sizes, int n_in,
                              void* d_out, int out_size, void* d_ws, size_t ws_size,
                              hipStream_t stream)
{
    const float* obs  = (const float*)d_in[0];
    const float* act  = (const float*)d_in[1];
    const float* inW  = (const float*)d_in[2];
    const float* inb  = (const float*)d_in[3];
    const float* qW   = (const float*)d_in[4];
    const float* qb   = (const float*)d_in[5];
    const float* kW   = (const float*)d_in[6];
    const float* kb   = (const float*)d_in[7];
    const float* vW   = (const float*)d_in[8];
    const float* vb   = (const float*)d_in[9];
    const float* oW   = (const float*)d_in[10];
    const float* ob   = (const float*)d_in[11];
    const float* outW = (const float*)d_in[12];
    const float* outb = (const float*)d_in[13];
    const float* lng  = (const float*)d_in[14];
    const float* lnb  = (const float*)d_in[15];
    float* outp = (float*)d_out;

    float* ws = (float*)d_ws;
    const size_t MD = (size_t)M_ * D_;
    float* x    = ws;
    float* qbuf = ws + MD;
    float* kbuf = ws + 2 * MD;
    float* vbuf = ws + 3 * MD;
    float* abuf = ws + 4 * MD;
    float* cosT = ws + 5 * MD;
    float* sinT = cosT + S_ * 16;

    rope_table_k<<<64, 256, 0, stream>>>(cosT, sinT);

    dim3 ggrid(4, 256);
    gemm_k<1,0><<<ggrid, 256, 0, stream>>>(nullptr, obs, act, inW, inb,
                                           nullptr, x, nullptr, nullptr);

    for (int l = 0; l < L_; ++l) {
        const float* qWl = qW + (size_t)l * D_ * D_;
        const float* kWl = kW + (size_t)l * D_ * D_;
        const float* vWl = vW + (size_t)l * D_ * D_;
        const float* oWl = oW + (size_t)l * D_ * D_;
        const float* qbl = qb + (size_t)l * D_;
        const float* kbl = kb + (size_t)l * D_;
        const float* vbl = vb + (size_t)l * D_;
        const float* obl = ob + (size_t)l * D_;

        gemm_k<0,3><<<ggrid, 256, 0, stream>>>(x, nullptr, nullptr, qWl, qbl,
                                               nullptr, qbuf, cosT, sinT);
        gemm_k<0,3><<<ggrid, 256, 0, stream>>>(x, nullptr, nullptr, kWl, kbl,
                                               nullptr, kbuf, cosT, sinT);
        gemm_k<0,2><<<ggrid, 256, 0, stream>>>(x, nullptr, nullptr, vWl, vbl,
                                               nullptr, vbuf, nullptr, nullptr);
        attn_k<<<256, 256, 0, stream>>>(qbuf, kbuf, vbuf, abuf);
        gemm_k<0,1><<<ggrid, 256, 0, stream>>>(abuf, nullptr, nullptr, oWl, obl,
                                               x, x, nullptr, nullptr);
    }

    gemm_k<0,0><<<ggrid, 256, 0, stream>>>(x, nullptr, nullptr, outW, outb,
                                           nullptr, qbuf, nullptr, nullptr);
    ln_k<<<M_ / 4, 256, 0, stream>>>(qbuf, lng, lnb, outp);
}

// Round 2
// 933.710 us; speedup vs baseline: 3.3070x; 3.3070x over previous
//
#include <hip/hip_runtime.h>
#include <hip/hip_bf16.h>
#include <math.h>

#define B_ 16
#define S_ 1024
#define D_ 256
#define H_ 8
#define L_ 4
#define DH_ 32
#define OBS_ 160
#define ACT_ 96
#define M_ (B_*S_)   // 16384

typedef __attribute__((ext_vector_type(8))) short short8v;   // 8 bf16 (4 VGPR)
typedef __attribute__((ext_vector_type(4))) short short4v;   // 4 bf16 (8B)
typedef __attribute__((ext_vector_type(4))) float f32x4;

__device__ inline short bf16rnd(float x) {
    unsigned u = __builtin_bit_cast(unsigned, x);
    return (short)((u + 0x8000u) >> 16);
}

// ---------------------------------------------------------------- RoPE table
__global__ __launch_bounds__(256) void rope_table_k(float* __restrict__ cosT,
                                                    float* __restrict__ sinT) {
    int idx = blockIdx.x * 256 + threadIdx.x;
    if (idx >= S_ * 16) return;
    int s = idx >> 4, i = idx & 15;
    float e = (float)(2 * i) / (float)DH_;
    float invf = powf(10000.0f, -e);
    float ang = (float)s * invf;
    float sn, cs;
    sincosf(ang, &sn, &cs);
    cosT[idx] = cs;
    sinT[idx] = sn;
}

// ---------------------------------------------------------------- GEMM
// C(M x 256) = A(M x 256) @ W(256 x 256) + bias  [+ residual]
// AMODE: 0 = plain A, 1 = concat(obs,act)
// EPI: 0 = f32 store, 1 = f32 + residual,
//      2 = bf16 transposed heads (B,H,DH,S)  [V path]
//      3 = bf16 heads (B,H,S,DH) + rope + scale [Q/K path]
template<int AMODE, int EPI>
__global__ __launch_bounds__(256) void gemm_k(
    const float* __restrict__ A, const float* __restrict__ obs,
    const float* __restrict__ act, const float* __restrict__ W,
    const float* __restrict__ bias, const float* __restrict__ resid,
    float* __restrict__ outF, short* __restrict__ outB,
    const float* __restrict__ cosT, const float* __restrict__ sinT,
    float scale)
{
    __shared__ float As[16][68];   // [k][m], padded
    __shared__ float Ws[16][64];   // [k][n]
    const int tid = threadIdx.x;
    const int tx = tid & 15, ty = tid >> 4;
    const int bcol = blockIdx.x * 64;
    const int brow = blockIdx.y * 64;

    const int arow = brow + (tid >> 2);
    const int ac0  = (tid & 3) * 4;
    const int wrow = tid >> 4;
    const int wc0  = (tid & 15) * 4;

    float acc[4][4];
    #pragma unroll
    for (int i = 0; i < 4; ++i)
        #pragma unroll
        for (int j = 0; j < 4; ++j) acc[i][j] = 0.f;

    for (int bk = 0; bk < 256; bk += 16) {
        float4 av, wv;
        if (AMODE == 0) {
            av = *(const float4*)&A[arow * 256 + bk + ac0];
        } else {
            int c = bk + ac0;
            if (c < OBS_) av = *(const float4*)&obs[arow * OBS_ + c];
            else          av = *(const float4*)&act[arow * ACT_ + (c - OBS_)];
        }
        wv = *(const float4*)&W[(bk + wrow) * 256 + bcol + wc0];
        __syncthreads();
        As[ac0 + 0][tid >> 2] = av.x;
        As[ac0 + 1][tid >> 2] = av.y;
        As[ac0 + 2][tid >> 2] = av.z;
        As[ac0 + 3][tid >> 2] = av.w;
        *(float4*)&Ws[wrow][wc0] = wv;
        __syncthreads();
        #pragma unroll
        for (int kk = 0; kk < 16; ++kk) {
            const float4 a = *(const float4*)&As[kk][ty * 4];
            const float4 b = *(const float4*)&Ws[kk][tx * 4];
            const float ar[4] = {a.x, a.y, a.z, a.w};
            const float br[4] = {b.x, b.y, b.z, b.w};
            #pragma unroll
            for (int i = 0; i < 4; ++i)
                #pragma unroll
                for (int j = 0; j < 4; ++j)
                    acc[i][j] = fmaf(ar[i], br[j], acc[i][j]);
        }
    }

    const int col = bcol + tx * 4;
    if (EPI <= 1) {
        #pragma unroll
        for (int i = 0; i < 4; ++i) {
            int row = brow + ty * 4 + i;
            float4 o;
            o.x = acc[i][0] + bias[col + 0];
            o.y = acc[i][1] + bias[col + 1];
            o.z = acc[i][2] + bias[col + 2];
            o.w = acc[i][3] + bias[col + 3];
            if (EPI == 1) {
                const float4 r = *(const float4*)&resid[row * 256 + col];
                o.x += r.x; o.y += r.y; o.z += r.z; o.w += r.w;
            }
            *(float4*)&outF[row * 256 + col] = o;
        }
    } else if (EPI == 3) {
        // Q/K: rope + scale, bf16, (B,H,S,DH)
        const int h  = col >> 5;
        const int dh = col & 31;
        const float b0 = bias[col + 0], b1 = bias[col + 1];
        const float b2 = bias[col + 2], b3 = bias[col + 3];
        #pragma unroll
        for (int i = 0; i < 4; ++i) {
            int row = brow + ty * 4 + i;
            int bb = row >> 10, ss = row & (S_ - 1);
            float v0 = (acc[i][0] + b0) * scale, v1 = (acc[i][1] + b1) * scale;
            float v2 = (acc[i][2] + b2) * scale, v3 = (acc[i][3] + b3) * scale;
            int ip = dh >> 1;
            float cs0 = cosT[ss * 16 + ip],     sn0 = sinT[ss * 16 + ip];
            float cs1 = cosT[ss * 16 + ip + 1], sn1 = sinT[ss * 16 + ip + 1];
            float o0 = v0 * cs0 - v1 * sn0;
            float o1 = v0 * sn0 + v1 * cs0;
            float o2 = v2 * cs1 - v3 * sn1;
            float o3 = v2 * sn1 + v3 * cs1;
            short4v pk = { bf16rnd(o0), bf16rnd(o1), bf16rnd(o2), bf16rnd(o3) };
            int base = ((bb * H_ + h) * S_ + ss) * DH_ + dh;
            *(short4v*)&outB[base] = pk;
        }
    } else {
        // V: bf16 transposed to (B,H,DH,S) via LDS transpose
        __shared__ short T[64][72];   // [col][row], padded
        #pragma unroll
        for (int j = 0; j < 4; ++j) {
            float bj = bias[col + j];
            short4v pk = { bf16rnd(acc[0][j] + bj), bf16rnd(acc[1][j] + bj),
                           bf16rnd(acc[2][j] + bj), bf16rnd(acc[3][j] + bj) };
            *(short4v*)&T[tx * 4 + j][ty * 4] = pk;
        }
        __syncthreads();
        const int c  = tid >> 2;          // 0..63 col within tile
        const int t0 = (tid & 3) * 16;    // token chunk
        const int colg = bcol + c;
        const int h = colg >> 5, dh = colg & 31;
        const int bb = brow >> 10, ss = (brow & (S_ - 1)) + t0;
        uint4 r0 = *(const uint4*)&T[c][t0];
        uint4 r1 = *(const uint4*)&T[c][t0 + 8];
        size_t base = ((size_t)((bb * H_ + h) * DH_ + dh)) * S_ + ss;
        *(uint4*)&outB[base]     = r0;
        *(uint4*)&outB[base + 8] = r1;
    }
}

// ---------------------------------------------------------------- Attention
// qb,kb: bf16 (B,H,S,DH) (q pre-scaled by 1/sqrt(DH), both rope'd)
// vtb:   bf16 (B,H,DH,S)
// out:   f32 (B,S,D)
__global__ __launch_bounds__(256) void attn_k(
    const short* __restrict__ qb, const short* __restrict__ kb,
    const short* __restrict__ vtb, float* __restrict__ out)
{
    __shared__ __align__(16) short P[4][16][40];   // per-wave P tile [q][key]
    const int tid  = threadIdx.x;
    const int wid  = tid >> 6, lane = tid & 63;
    const int n    = blockIdx.x;
    const int head = n & 127;        // b*H+h
    const int qt   = n >> 7;         // 0..15
    const int q0   = qt * 64 + wid * 16;
    const int ql   = lane & 15;
    const int g    = lane >> 4;      // 0..3

    const short* qrow  = qb  + ((size_t)(head * S_ + q0 + ql)) * DH_ + g * 8;
    const short8v Qf   = *(const short8v*)qrow;
    const short* kbase = kb  + (size_t)head * S_ * DH_;
    const short* vbase = vtb + (size_t)head * DH_ * S_;

    f32x4 accA = {0.f, 0.f, 0.f, 0.f};
    f32x4 accB = {0.f, 0.f, 0.f, 0.f};
    const f32x4 zero = {0.f, 0.f, 0.f, 0.f};
    float m = -3e38f, lsum = 0.f;

    for (int kk = 0; kk < S_; kk += 32) {
        short8v K0 = *(const short8v*)&kbase[(size_t)(kk + ql) * DH_ + g * 8];
        short8v K1 = *(const short8v*)&kbase[(size_t)(kk + 16 + ql) * DH_ + g * 8];
        short8v V0 = *(const short8v*)&vbase[(size_t)ql * S_ + kk + g * 8];
        short8v V1 = *(const short8v*)&vbase[(size_t)(16 + ql) * S_ + kk + g * 8];

        f32x4 s0 = __builtin_amdgcn_mfma_f32_16x16x32_bf16(K0, Qf, zero, 0, 0, 0);
        f32x4 s1 = __builtin_amdgcn_mfma_f32_16x16x32_bf16(K1, Qf, zero, 0, 0, 0);

        float pm = fmaxf(fmaxf(fmaxf(s0[0], s0[1]), fmaxf(s0[2], s0[3])),
                         fmaxf(fmaxf(s1[0], s1[1]), fmaxf(s1[2], s1[3])));
        pm = fmaxf(pm, __shfl_xor(pm, 16));
        pm = fmaxf(pm, __shfl_xor(pm, 32));
        float mn = fmaxf(m, pm);
        float c  = __expf(m - mn);
        m = mn;

        float p0 = __expf(s0[0] - mn), p1 = __expf(s0[1] - mn);
        float p2 = __expf(s0[2] - mn), p3 = __expf(s0[3] - mn);
        float p4 = __expf(s1[0] - mn), p5 = __expf(s1[1] - mn);
        float p6 = __expf(s1[2] - mn), p7 = __expf(s1[3] - mn);
        lsum = lsum * c + ((p0 + p1) + (p2 + p3)) + ((p4 + p5) + (p6 + p7));

        short4v w0 = { bf16rnd(p0), bf16rnd(p1), bf16rnd(p2), bf16rnd(p3) };
        short4v w1 = { bf16rnd(p4), bf16rnd(p5), bf16rnd(p6), bf16rnd(p7) };
        *(short4v*)&P[wid][ql][4 * g]      = w0;
        *(short4v*)&P[wid][ql][16 + 4 * g] = w1;
        short8v Pf = *(const short8v*)&P[wid][ql][8 * g];

        accA *= c;
        accB *= c;
        accA = __builtin_amdgcn_mfma_f32_16x16x32_bf16(V0, Pf, accA, 0, 0, 0);
        accB = __builtin_amdgcn_mfma_f32_16x16x32_bf16(V1, Pf, accB, 0, 0, 0);
    }

    lsum += __shfl_xor(lsum, 16);
    lsum += __shfl_xor(lsum, 32);
    float inv = 1.f / lsum;

    const int bb = head >> 3, hh = head & 7;
    const int s  = q0 + ql;
    float* op = out + ((size_t)(bb * S_ + s)) * D_ + hh * DH_;
    f32x4 oA = accA * inv;
    f32x4 oB = accB * inv;
    *(f32x4*)&op[4 * g]      = oA;
    *(f32x4*)&op[16 + 4 * g] = oB;
}

// ---------------------------------------------------------------- LayerNorm
__global__ __launch_bounds__(256) void ln_k(
    const float* __restrict__ y, const float* __restrict__ g,
    const float* __restrict__ bta, float* __restrict__ outp)
{
    const int tid = threadIdx.x;
    const int wave = tid >> 6, lane = tid & 63;
    const int row = blockIdx.x * 4 + wave;
    const int col = lane * 4;
    float4 t = *(const float4*)&y[row * 256 + col];
    float sum = t.x + t.y + t.z + t.w;
    float ss  = t.x*t.x + t.y*t.y + t.z*t.z + t.w*t.w;
    #pragma unroll
    for (int off = 32; off; off >>= 1) {
        sum += __shfl_xor(sum, off);
        ss  += __shfl_xor(ss, off);
    }
    float mean = sum * (1.f / 256.f);
    float var  = ss * (1.f / 256.f) - mean * mean;
    float rstd = rsqrtf(var + 1e-5f);
    float4 gv = *(const float4*)&g[col];
    float4 bv = *(const float4*)&bta[col];
    float4 o;
    o.x = (t.x - mean) * rstd * gv.x + bv.x;
    o.y = (t.y - mean) * rstd * gv.y + bv.y;
    o.z = (t.z - mean) * rstd * gv.z + bv.z;
    o.w = (t.w - mean) * rstd * gv.w + bv.w;
    float* seq = outp + B_ * D_;
    *(float4*)&seq[row * 256 + col] = o;
    if ((row & (S_ - 1)) == S_ - 1) {
        *(float4*)&outp[(row >> 10) * 256 + col] = o;
    }
}

// ---------------------------------------------------------------- launch
extern "C" void kernel_launch(void* const* d_in, const int* in_sizes, int n_in,
                              void* d_out, int out_size, void* d_ws, size_t ws_size,
                              hipStream_t stream)
{
    const float* obs  = (const float*)d_in[0];
    const float* act  = (const float*)d_in[1];
    const float* inW  = (const float*)d_in[2];
    const float* inb  = (const float*)d_in[3];
    const float* qW   = (const float*)d_in[4];
    const float* qb_  = (const float*)d_in[5];
    const float* kW   = (const float*)d_in[6];
    const float* kb_  = (const float*)d_in[7];
    const float* vW   = (const float*)d_in[8];
    const float* vb_  = (const float*)d_in[9];
    const float* oW   = (const float*)d_in[10];
    const float* ob_  = (const float*)d_in[11];
    const float* outW = (const float*)d_in[12];
    const float* outb = (const float*)d_in[13];
    const float* lng  = (const float*)d_in[14];
    const float* lnb  = (const float*)d_in[15];
    float* outp = (float*)d_out;

    float* ws = (float*)d_ws;
    const size_t MD = (size_t)M_ * D_;
    float* x    = ws;                 // f32 activations
    float* abuf = ws + MD;            // f32 attention out / final y
    float* cosT = ws + 2 * MD;
    float* sinT = cosT + S_ * 16;
    short* qbf  = (short*)(sinT + S_ * 16);   // bf16 Q (B,H,S,DH)
    short* kbf  = qbf + MD;                   // bf16 K (B,H,S,DH)
    short* vtb  = kbf + MD;                   // bf16 V^T (B,H,DH,S)

    const float qscale = 0.17677669529663687f;   // 1/sqrt(32)

    rope_table_k<<<64, 256, 0, stream>>>(cosT, sinT);

    dim3 ggrid(4, 256);
    gemm_k<1,0><<<ggrid, 256, 0, stream>>>(nullptr, obs, act, inW, inb,
                                           nullptr, x, nullptr, nullptr, nullptr, 1.f);

    for (int l = 0; l < L_; ++l) {
        const float* qWl = qW + (size_t)l * D_ * D_;
        const float* kWl = kW + (size_t)l * D_ * D_;
        const float* vWl = vW + (size_t)l * D_ * D_;
        const float* oWl = oW + (size_t)l * D_ * D_;
        const float* qbl = qb_ + (size_t)l * D_;
        const float* kbl = kb_ + (size_t)l * D_;
        const float* vbl = vb_ + (size_t)l * D_;
        const float* obl = ob_ + (size_t)l * D_;

        gemm_k<0,3><<<ggrid, 256, 0, stream>>>(x, nullptr, nullptr, qWl, qbl,
                                               nullptr, nullptr, qbf, cosT, sinT, qscale);
        gemm_k<0,3><<<ggrid, 256, 0, stream>>>(x, nullptr, nullptr, kWl, kbl,
                                               nullptr, nullptr, kbf, cosT, sinT, 1.f);
        gemm_k<0,2><<<ggrid, 256, 0, stream>>>(x, nullptr, nullptr, vWl, vbl,
                                               nullptr, nullptr, vtb, nullptr, nullptr, 1.f);
        attn_k<<<2048, 256, 0, stream>>>(qbf, kbf, vtb, abuf);
        gemm_k<0,1><<<ggrid, 256, 0, stream>>>(abuf, nullptr, nullptr, oWl, obl,
                                               x, x, nullptr, nullptr, nullptr, 1.f);
    }

    gemm_k<0,0><<<ggrid, 256, 0, stream>>>(x, nullptr, nullptr, outW, outb,
                                           nullptr, abuf, nullptr, nullptr, nullptr, 1.f);
    ln_k<<<M_ / 4, 256, 0, stream>>>(abuf, lng, lnb, outp);
}

// Round 3
// 373.004 us; speedup vs baseline: 8.2780x; 2.5032x over previous
//
#include <hip/hip_runtime.h>
#include <hip/hip_bf16.h>
#include <math.h>

#define B_ 16
#define S_ 1024
#define D_ 256
#define H_ 8
#define L_ 4
#define DH_ 32
#define OBS_ 160
#define ACT_ 96
#define M_ (B_*S_)   // 16384

typedef __attribute__((ext_vector_type(8)))  short short8v;   // 8 bf16
typedef __attribute__((ext_vector_type(4)))  short short4v;   // 4 bf16
typedef __attribute__((ext_vector_type(4)))  float f32x4;
typedef __attribute__((ext_vector_type(16))) float f32x16;
typedef __attribute__((ext_vector_type(4)))  unsigned uint4v;

#define ALPHA_ 0.25507313f   // log2(e)/sqrt(32)
#define THRRAW_ 31.3635f     // 8 / ALPHA_

__device__ inline short bf16rne(float x) {
    unsigned u = __builtin_bit_cast(unsigned, x);
    unsigned r = (u + 0x7fffu + ((u >> 16) & 1u)) >> 16;
    return (short)r;
}

#if __has_builtin(__builtin_amdgcn_exp2f)
#define EXP2F(x) __builtin_amdgcn_exp2f(x)
#else
#define EXP2F(x) exp2f(x)
#endif

__device__ inline unsigned cvtpk_bf16(float lo, float hi) {
    unsigned r;
    asm("v_cvt_pk_bf16_f32 %0, %1, %2" : "=v"(r) : "v"(lo), "v"(hi));
    return r;
}

// lane<32 half / lane>=32 half exchange (safe shfl version of permlane32_swap):
// rx[l] = l<32 ? b[l+32] : a[l];  ry[l] = l<32 ? b[l] : a[l-32]
__device__ inline void plswap(unsigned a, unsigned b, bool lo,
                              unsigned& rx, unsigned& ry) {
    unsigned ax = (unsigned)__shfl_xor((int)a, 32);
    unsigned bx = (unsigned)__shfl_xor((int)b, 32);
    rx = lo ? bx : a;
    ry = lo ? b  : ax;
}

// ------------------------------------------------------------ RoPE table
// Transposed layout [i=0..15][s=0..1023] so GEMM epilogue can vector-load
// cos/sin along 4 consecutive s (the MFMA C fragment's 4 rows).
__global__ __launch_bounds__(256) void rope_table_k(float* __restrict__ cosT2,
                                                    float* __restrict__ sinT2) {
    int idx = blockIdx.x * 256 + threadIdx.x;   // 16384
    int i = idx >> 10, s = idx & 1023;
    float invf = powf(10000.0f, -(float)(2 * i) / 32.0f);
    float ang = (float)s * invf;
    float sn, cs;
    sincosf(ang, &sn, &cs);
    cosT2[idx] = cs;
    sinT2[idx] = sn;
}

// ------------------------------------------------------------ input concat+cvt
__global__ __launch_bounds__(256) void cvt_in_k(const float* __restrict__ obs,
                                                const float* __restrict__ act,
                                                short* __restrict__ xIn) {
    const int idx = (blockIdx.x * 256 + threadIdx.x) * 8;
    const int row = idx >> 8, col = idx & 255;
    const float* s = (col < OBS_) ? (obs + (size_t)row * OBS_ + col)
                                  : (act + (size_t)row * ACT_ + (col - OBS_));
    const float4 v0 = *(const float4*)s;
    const float4 v1 = *(const float4*)(s + 4);
    short8v o = {bf16rne(v0.x), bf16rne(v0.y), bf16rne(v0.z), bf16rne(v0.w),
                 bf16rne(v1.x), bf16rne(v1.y), bf16rne(v1.z), bf16rne(v1.w)};
    *(short8v*)&xIn[idx] = o;
}

// ------------------------------------------------------------ weight cvt+transpose
// All 18 256x256 f32 weight matrices -> bf16 W^T [N][K] row-major (B-operand
// wants k-contiguous per n-row).
__global__ __launch_bounds__(256) void wconv_k(
    const float* __restrict__ qW, const float* __restrict__ kW,
    const float* __restrict__ vW, const float* __restrict__ oW,
    const float* __restrict__ outW, const float* __restrict__ inW,
    short* __restrict__ WTqkv, short* __restrict__ WTo,
    short* __restrict__ WTf, short* __restrict__ WTin)
{
    __shared__ float T[64][65];
    const int z = blockIdx.y;           // 0..17
    const int bx = blockIdx.x;          // 0..15
    const int tr = (bx & 3) * 64, tc = (bx >> 2) * 64;
    const float* src;
    short* dst;
    if (z < 16) {
        int lay = z >> 2, w = z & 3;
        if (w == 0)      { src = qW + lay * 65536; dst = WTqkv + lay * 196608; }
        else if (w == 1) { src = kW + lay * 65536; dst = WTqkv + lay * 196608 + 65536; }
        else if (w == 2) { src = vW + lay * 65536; dst = WTqkv + lay * 196608 + 131072; }
        else             { src = oW + lay * 65536; dst = WTo + lay * 65536; }
    } else if (z == 16) { src = outW; dst = WTf; }
    else                { src = inW;  dst = WTin; }
    const int tid = threadIdx.x;
    #pragma unroll
    for (int it = 0; it < 4; ++it) {
        int r = (tid >> 4) + it * 16, c = (tid & 15) * 4;
        *(float4*)&T[r][c] = *(const float4*)&src[(size_t)(tr + r) * 256 + tc + c];
    }
    __syncthreads();
    #pragma unroll
    for (int it = 0; it < 4; ++it) {
        int n = (tid >> 4) + it * 16, k = (tid & 15) * 4;
        short4v o = {bf16rne(T[k][n]), bf16rne(T[k + 1][n]),
                     bf16rne(T[k + 2][n]), bf16rne(T[k + 3][n])};
        *(short4v*)&dst[(size_t)(tc + n) * 256 + tr + k] = o;
    }
}

// ------------------------------------------------------------ MFMA GEMM
// C(MxN) = A(Mx256, bf16) @ W(256xN) + bias, via WT[N][256] bf16.
// BM=128 BN=64 BK=32; 4 waves, wave tile 64x32 (4x2 16x16 frags).
// EPI 0: QKV fused (N=768): Q/K -> rope -> (B,H,DH,S) bf16; V -> (B,H,DH,S) bf16
// EPI 1: + residual xF -> xF(f32) + xB(bf16)
// EPI 2: -> xF + xB
// EPI 3: -> yF (f32)
template<int EPI>
__global__ __launch_bounds__(256) void gemm_k(
    const short* __restrict__ A, const short* __restrict__ WT,
    const float* __restrict__ bq, const float* __restrict__ bk,
    const float* __restrict__ bv,
    float* __restrict__ xF, short* __restrict__ xB,
    short* __restrict__ QT, short* __restrict__ KT, short* __restrict__ VT,
    float* __restrict__ yF,
    const float* __restrict__ cosT2, const float* __restrict__ sinT2)
{
    __shared__ short As[2][128 * 32];
    __shared__ short Bs[2][64 * 32];
    const int tid = threadIdx.x;
    const int l = tid & 63;
    const int wid = tid >> 6, wr = wid >> 1, wc = wid & 1;
    const int bn = blockIdx.x * 64, bm = blockIdx.y * 128;

    // staging: thread t owns A chunks t and t+256, B chunk t (16B each)
    const short* aSrc0 = A + (size_t)(bm + (tid >> 2)) * 256 + (tid & 3) * 8;
    const short* aSrc1 = aSrc0 + 64 * 256;
    const short* bSrc  = WT + (size_t)(bn + (tid >> 2)) * 256 + (tid & 3) * 8;

    short8v a0 = *(const short8v*)aSrc0;
    short8v a1 = *(const short8v*)aSrc1;
    short8v b0 = *(const short8v*)bSrc;
    *(short8v*)&As[0][tid * 8]         = a0;
    *(short8v*)&As[0][(tid + 256) * 8] = a1;
    *(short8v*)&Bs[0][tid * 8]         = b0;
    __syncthreads();

    f32x4 acc[4][2];
    #pragma unroll
    for (int i = 0; i < 4; ++i)
        #pragma unroll
        for (int j = 0; j < 2; ++j) acc[i][j] = (f32x4){0.f, 0.f, 0.f, 0.f};

    #pragma unroll
    for (int t = 0; t < 8; ++t) {
        const int cur = t & 1;
        short8v na0, na1, nb;
        if (t < 7) {                    // issue next-tile loads before MFMA
            const int k = (t + 1) * 32;
            na0 = *(const short8v*)&aSrc0[k];
            na1 = *(const short8v*)&aSrc1[k];
            nb  = *(const short8v*)&bSrc[k];
        }
        short8v af[4], bf[2];
        #pragma unroll
        for (int i = 0; i < 4; ++i)
            af[i] = *(const short8v*)&As[cur][(wr * 64 + i * 16 + (l & 15)) * 32 + (l >> 4) * 8];
        #pragma unroll
        for (int j = 0; j < 2; ++j)
            bf[j] = *(const short8v*)&Bs[cur][(wc * 32 + j * 16 + (l & 15)) * 32 + (l >> 4) * 8];
        #pragma unroll
        for (int i = 0; i < 4; ++i)
            #pragma unroll
            for (int j = 0; j < 2; ++j)
                acc[i][j] = __builtin_amdgcn_mfma_f32_16x16x32_bf16(af[i], bf[j], acc[i][j], 0, 0, 0);
        if (t < 7) {
            const int nxt = cur ^ 1;
            *(short8v*)&As[nxt][tid * 8]         = na0;
            *(short8v*)&As[nxt][(tid + 256) * 8] = na1;
            *(short8v*)&Bs[nxt][tid * 8]         = nb;
            __syncthreads();
        }
    }

    // ---------------- epilogue (C frag: col = l&15, rows = (l>>4)*4 + 0..3)
    const int region = (EPI == 0) ? ((bn + wc * 32) >> 8) : 0;
    const float* bias = (EPI == 0)
        ? (region == 0 ? bq : region == 1 ? bk : bv) : bq;
    #pragma unroll
    for (int i = 0; i < 4; ++i) {
        const int m0 = bm + wr * 64 + i * 16 + ((l >> 4) << 2);
        #pragma unroll
        for (int j = 0; j < 2; ++j) {
            const int nn = bn + wc * 32 + j * 16 + (l & 15);
            f32x4 v = acc[i][j];
            if (EPI == 0) {
                const int nl = nn & 255;
                const float bb = bias[nl];
                v[0] += bb; v[1] += bb; v[2] += bb; v[3] += bb;
                const int b = m0 >> 10, s0 = m0 & 1023;
                const int h = nl >> 5, dhh = nl & 31;
                if (region < 2) {
                    // fused RoPE: dh-pairs are adjacent lanes
                    const int ir = dhh >> 1;
                    const f32x4 cs = *(const f32x4*)&cosT2[ir * 1024 + s0];
                    const f32x4 sn = *(const f32x4*)&sinT2[ir * 1024 + s0];
                    f32x4 pr;
                    #pragma unroll
                    for (int c = 0; c < 4; ++c) pr[c] = __shfl_xor(v[c], 1);
                    const float sg = (nl & 1) ? 1.f : -1.f;
                    #pragma unroll
                    for (int c = 0; c < 4; ++c)
                        v[c] = v[c] * cs[c] + sg * pr[c] * sn[c];
                }
                short4v o = {bf16rne(v[0]), bf16rne(v[1]), bf16rne(v[2]), bf16rne(v[3])};
                short* dst = (region == 0) ? QT : (region == 1) ? KT : VT;
                *(short4v*)&dst[((size_t)((b * 8 + h) * 32 + dhh) << 10) + s0] = o;
            } else {
                const float bb = bias[nn];
                #pragma unroll
                for (int c = 0; c < 4; ++c) {
                    float r = v[c] + bb;
                    const size_t off = (size_t)(m0 + c) * 256 + nn;
                    if (EPI == 1) r += xF[off];
                    if (EPI == 3) {
                        yF[off] = r;
                    } else {
                        xF[off] = r;
                        xB[off] = bf16rne(r);
                    }
                }
            }
        }
    }
}

// ------------------------------------------------------------ Attention
// QT/KT/VT: bf16 (B,H,DH,S). Per block: 1 head x 128 q rows (4 waves x 32 q).
// Per wave: scores S^T[key][q] = mfma32x32x16(K,Q) x2 (dh halves); in-register
// softmax (lane owns 16 scores of its q); defer-max; cvt_pk + lane32-swap to
// build P as the PV B-operand; O^T[dh][q] += mfma(V,P) x2.
// Output: bf16 (B,S,D) for the O-projection.
__global__ __launch_bounds__(256) void attn_k(
    const short* __restrict__ QT, const short* __restrict__ KT,
    const short* __restrict__ VT, short* __restrict__ O)
{
    __shared__ short KS[2][1024];   // [dh 0..31][key 0..31] linear
    __shared__ short VS[2][1024];   // same, with 16B-chunk XOR swizzle
    const int tid = threadIdx.x;
    const int l = tid & 63, wid = tid >> 6;
    const int head = blockIdx.x & 127;          // b*8+h (keeps head on one XCD)
    const int qt = blockIdx.x >> 7;             // 0..7
    const int q0 = qt * 128 + wid * 32;
    const int lq = l & 31, hi = l >> 5;
    const bool lo = (hi == 0);

    const short* QTh = QT + (size_t)head * 32768;
    const short* KTh = KT + (size_t)head * 32768;
    const short* VTh = VT + (size_t)head * 32768;

    // Q B-fragments (once per block): element j = Q[q][dh=f*16+hi*8+j]
    short8v Qf0, Qf1;
    #pragma unroll
    for (int j = 0; j < 8; ++j) {
        Qf0[j] = QTh[(size_t)(hi * 8 + j) * 1024 + q0 + lq];
        Qf1[j] = QTh[(size_t)(16 + hi * 8 + j) * 1024 + q0 + lq];
    }

    // staging: threads 0-127 stage K (linear), 128-255 stage V (chunk-XOR)
    const int sc = tid & 127;
    const int sdh = sc >> 2, scp = sc & 3;
    const bool isK = (tid < 128);
    const int sch = isK ? scp : (scp ^ ((sdh >> 1) & 3));
    const short* sbase = (isK ? KTh : VTh) + sdh * 1024 + sch * 8;
    short* sd0 = (isK ? &KS[0][0] : &VS[0][0]) + sc * 8;
    short* sd1 = (isK ? &KS[1][0] : &VS[1][0]) + sc * 8;

    short8v st = *(const short8v*)sbase;
    *(short8v*)sd0 = st;
    __syncthreads();

    f32x16 acc = {0.f,0.f,0.f,0.f,0.f,0.f,0.f,0.f,0.f,0.f,0.f,0.f,0.f,0.f,0.f,0.f};
    float m = -3e30f, lsum = 0.f;

    for (int t = 0; t < 32; ++t) {
        const short* ks = (t & 1) ? &KS[1][0] : &KS[0][0];
        const short* vs = (t & 1) ? &VS[1][0] : &VS[0][0];

        // K A-frags via scalar LDS reads (bank-clean: key pairs share a dword)
        short8v Kf0, Kf1;
        #pragma unroll
        for (int j = 0; j < 8; ++j) {
            Kf0[j] = ks[(hi * 8 + j) * 32 + lq];
            Kf1[j] = ks[(16 + hi * 8 + j) * 32 + lq];
        }
        // V B-frags (16B, XOR-swizzled chunks)
        const int vx = (lq >> 1) & 3;
        short8v Vf0 = *(const short8v*)&vs[lq * 32 + ((hi ^ vx) << 3)];
        short8v Vf1 = *(const short8v*)&vs[lq * 32 + (((2 | hi) ^ vx) << 3)];

        short8v nst;
        if (t < 31) nst = *(const short8v*)&sbase[(t + 1) * 32];  // issue early

        f32x16 s = {0.f,0.f,0.f,0.f,0.f,0.f,0.f,0.f,0.f,0.f,0.f,0.f,0.f,0.f,0.f,0.f};
        s = __builtin_amdgcn_mfma_f32_32x32x16_bf16(Kf0, Qf0, s, 0, 0, 0);
        s = __builtin_amdgcn_mfma_f32_32x32x16_bf16(Kf1, Qf1, s, 0, 0, 0);

        float pm = s[0];
        #pragma unroll
        for (int r = 1; r < 16; ++r) pm = fmaxf(pm, s[r]);
        pm = fmaxf(pm, __shfl_xor(pm, 32));

        if (!__all(pm <= m + THRRAW_)) {         // defer-max rescale
            float mn = fmaxf(m, pm);
            float c = EXP2F((m - mn) * ALPHA_);
            lsum *= c;
            #pragma unroll
            for (int r = 0; r < 16; ++r) acc[r] *= c;
            m = mn;
        }
        const float nma = -m * ALPHA_;
        float p[16];
        #pragma unroll
        for (int r = 0; r < 16; ++r) p[r] = EXP2F(fmaf(s[r], ALPHA_, nma));
        float ls = 0.f;
        #pragma unroll
        for (int r = 0; r < 16; ++r) ls += p[r];
        lsum += ls;

        // pack P -> bf16 pairs; redistribute halves for the B-operand layout
        unsigned u0 = cvtpk_bf16(p[0],  p[1]),  u1 = cvtpk_bf16(p[2],  p[3]);
        unsigned u2 = cvtpk_bf16(p[4],  p[5]),  u3 = cvtpk_bf16(p[6],  p[7]);
        unsigned u4 = cvtpk_bf16(p[8],  p[9]),  u5 = cvtpk_bf16(p[10], p[11]);
        unsigned u6 = cvtpk_bf16(p[12], p[13]), u7 = cvtpk_bf16(p[14], p[15]);
        unsigned w0, w1, w2, w3;
        plswap(u2, u0, lo, w2, w0);
        plswap(u3, u1, lo, w3, w1);
        uint4v P1v = {w0, w1, w2, w3};
        plswap(u6, u4, lo, w2, w0);
        plswap(u7, u5, lo, w3, w1);
        uint4v P2v = {w0, w1, w2, w3};
        short8v Pf1 = __builtin_bit_cast(short8v, P1v);
        short8v Pf2 = __builtin_bit_cast(short8v, P2v);

        acc = __builtin_amdgcn_mfma_f32_32x32x16_bf16(Vf0, Pf1, acc, 0, 0, 0);
        acc = __builtin_amdgcn_mfma_f32_32x32x16_bf16(Vf1, Pf2, acc, 0, 0, 0);

        if (t < 31) {
            short* sd = (t & 1) ? sd0 : sd1;     // next buffer
            *(short8v*)sd = nst;
        }
        __syncthreads();
    }

    lsum += __shfl_xor(lsum, 32);
    const float inv = 1.f / lsum;
    const int bI = head >> 3, hh = head & 7;
    const int srow = q0 + lq;
    #pragma unroll
    for (int c = 0; c < 4; ++c) {
        short4v o = {bf16rne(acc[4 * c + 0] * inv), bf16rne(acc[4 * c + 1] * inv),
                     bf16rne(acc[4 * c + 2] * inv), bf16rne(acc[4 * c + 3] * inv)};
        *(short4v*)&O[(size_t)(bI * 1024 + srow) * 256 + hh * 32 + c * 8 + hi * 4] = o;
    }
}

// ------------------------------------------------------------ LayerNorm
__global__ __launch_bounds__(256) void ln_k(
    const float* __restrict__ y, const float* __restrict__ g,
    const float* __restrict__ bta, float* __restrict__ outp)
{
    const int tid = threadIdx.x;
    const int wave = tid >> 6, lane = tid & 63;
    const int row = blockIdx.x * 4 + wave;
    const int col = lane * 4;
    float4 t = *(const float4*)&y[(size_t)row * 256 + col];
    float sum = t.x + t.y + t.z + t.w;
    float ss  = t.x * t.x + t.y * t.y + t.z * t.z + t.w * t.w;
    #pragma unroll
    for (int off = 32; off; off >>= 1) {
        sum += __shfl_xor(sum, off);
        ss  += __shfl_xor(ss, off);
    }
    float mean = sum * (1.f / 256.f);
    float var  = ss * (1.f / 256.f) - mean * mean;
    float rstd = rsqrtf(var + 1e-5f);
    float4 gv = *(const float4*)&g[col];
    float4 bv = *(const float4*)&bta[col];
    float4 o;
    o.x = (t.x - mean) * rstd * gv.x + bv.x;
    o.y = (t.y - mean) * rstd * gv.y + bv.y;
    o.z = (t.z - mean) * rstd * gv.z + bv.z;
    o.w = (t.w - mean) * rstd * gv.w + bv.w;
    float* seq = outp + B_ * D_;
    *(float4*)&seq[(size_t)row * 256 + col] = o;
    if ((row & (S_ - 1)) == S_ - 1)
        *(float4*)&outp[(size_t)(row >> 10) * 256 + col] = o;
}

// ------------------------------------------------------------ launch
extern "C" void kernel_launch(void* const* d_in, const int* in_sizes, int n_in,
                              void* d_out, int out_size, void* d_ws, size_t ws_size,
                              hipStream_t stream)
{
    const float* obs  = (const float*)d_in[0];
    const float* act  = (const float*)d_in[1];
    const float* inW  = (const float*)d_in[2];
    const float* inb  = (const float*)d_in[3];
    const float* qW   = (const float*)d_in[4];
    const float* qb   = (const float*)d_in[5];
    const float* kW   = (const float*)d_in[6];
    const float* kb   = (const float*)d_in[7];
    const float* vW   = (const float*)d_in[8];
    const float* vb   = (const float*)d_in[9];
    const float* oW   = (const float*)d_in[10];
    const float* ob   = (const float*)d_in[11];
    const float* outW = (const float*)d_in[12];
    const float* outb = (const float*)d_in[13];
    const float* lng  = (const float*)d_in[14];
    const float* lnb  = (const float*)d_in[15];
    float* outp = (float*)d_out;

    const size_t MD = (size_t)M_ * D_;   // 4,194,304
    float* xF    = (float*)d_ws;         // f32 residual stream
    short* xB    = (short*)(xF + MD);    // bf16 mirror of xF
    short* xIn   = xB + MD;              // bf16 concat(obs,act)
    short* QT    = xIn + MD;             // bf16 (B,H,DH,S)
    short* KT    = QT + MD;
    short* VT    = KT + MD;
    short* Obf   = VT + MD;              // bf16 attn out (B,S,D)
    short* WTqkv = Obf + MD;             // 4 x [768][256]
    short* WTo   = WTqkv + 786432;       // 4 x [256][256]
    short* WTf   = WTo + 262144;
    short* WTin  = WTf + 65536;
    float* cosT2 = (float*)(WTin + 65536);  // [16][1024]
    float* sinT2 = cosT2 + 16384;
    float* ybuf  = (float*)QT;           // alias: QT/KT dead before final GEMM

    rope_table_k<<<64, 256, 0, stream>>>(cosT2, sinT2);
    cvt_in_k<<<2048, 256, 0, stream>>>(obs, act, xIn);
    wconv_k<<<dim3(16, 18), 256, 0, stream>>>(qW, kW, vW, oW, outW, inW,
                                              WTqkv, WTo, WTf, WTin);

    gemm_k<2><<<dim3(4, 128), 256, 0, stream>>>(xIn, WTin, inb, nullptr, nullptr,
            xF, xB, nullptr, nullptr, nullptr, nullptr, nullptr, nullptr);

    for (int lay = 0; lay < L_; ++lay) {
        gemm_k<0><<<dim3(12, 128), 256, 0, stream>>>(xB, WTqkv + lay * 196608,
                qb + lay * 256, kb + lay * 256, vb + lay * 256,
                nullptr, nullptr, QT, KT, VT, nullptr, cosT2, sinT2);
        attn_k<<<1024, 256, 0, stream>>>(QT, KT, VT, Obf);
        gemm_k<1><<<dim3(4, 128), 256, 0, stream>>>(Obf, WTo + lay * 65536,
                ob + lay * 256, nullptr, nullptr, xF, xB,
                nullptr, nullptr, nullptr, nullptr, nullptr, nullptr);
    }

    gemm_k<3><<<dim3(4, 128), 256, 0, stream>>>(xB, WTf, outb, nullptr, nullptr,
            nullptr, nullptr, nullptr, nullptr, nullptr, ybuf, nullptr, nullptr);
    ln_k<<<M_ / 4, 256, 0, stream>>>(ybuf, lng, lnb, outp);
}